// Round 9
// baseline (363.523 us; speedup 1.0000x reference)
//
#include <hip/hip_runtime.h>
#include <hip/hip_bf16.h>
#include <stdint.h>

#define B_   8
#define NS_  8192
#define E_   32
#define NT_  8192
#define NH_  10
#define NCH_ 128   // NS_/64 K-chunks
#define CAND_CAP 256

typedef __bf16 bf16x8 __attribute__((ext_vector_type(8)));
typedef float  f32x4  __attribute__((ext_vector_type(4)));
typedef unsigned short ushort8_t __attribute__((ext_vector_type(8)));
typedef unsigned short ushort4_t __attribute__((ext_vector_type(4)));

static __device__ inline unsigned short f2bf(float f) {
  __hip_bfloat16 h = __float2bfloat16(f);
  return *reinterpret_cast<unsigned short*>(&h);
}
static __device__ inline float bf2f(unsigned short u) {
  __hip_bfloat16 h;
  *reinterpret_cast<unsigned short*>(&h) = u;
  return __bfloat162float(h);
}

// ---------------------------------------------------------------------------
// Kernel A: per-target-row top-10 smallest d = sqrt(lon^2+lat^2).
// v9: two-pass threshold filter.
//  Pass A: d2 = fmaf(lon,lon, lat*lat); per-lane running min (no sqrt, no
//          cascade). T1 = 10th-smallest of 64 lane minima (valid upper bound
//          on true 10th-smallest d2: the 10 smallest lane minima are 10
//          distinct row elements).
//  Pass B: re-scan (L3-resident), collect s with d2 <= T1*1.000002 into LDS
//          (margin covers fma-vs-strict 1ulp + sqrt-collision d-ties).
//  Final:  <=256 candidates -> BIT-EXACT strict d (__f*_rn, the verified
//          sequence), key (d_bits<<32)|s, original cascade + wave merge ->
//          outputs identical to numpy incl. all tie-breaking.
// ---------------------------------------------------------------------------
__global__ __launch_bounds__(256) void topk_kernel(
    const float* __restrict__ rel_lon, const float* __restrict__ rel_lat,
    float* __restrict__ out_d, float* __restrict__ out_lon,
    float* __restrict__ out_lat, int* __restrict__ idx_out)
{
  __shared__ int cnt[4];
  __shared__ unsigned int cand[4][CAND_CAP];

  const int wave = threadIdx.x >> 6;
  const int lane = threadIdx.x & 63;
  const int t = blockIdx.x * 4 + wave;
  const float* lon_row = rel_lon + (size_t)t * NS_;
  const float* lat_row = rel_lat + (size_t)t * NS_;

  if (lane == 0) cnt[wave] = 0;

  // ---- Pass A: per-lane min of d2 (fma form, filter-only) ----
  float lmin = __uint_as_float(0x7f800000u);  // +inf
  for (int c = 0; c < NS_; c += 256) {
    const int s = c + lane * 4;
    const float4 lo4 = *(const float4*)(lon_row + s);
    const float4 la4 = *(const float4*)(lat_row + s);
    const float d0 = __fmaf_rn(lo4.x, lo4.x, __fmul_rn(la4.x, la4.x));
    const float d1 = __fmaf_rn(lo4.y, lo4.y, __fmul_rn(la4.y, la4.y));
    const float d2 = __fmaf_rn(lo4.z, lo4.z, __fmul_rn(la4.z, la4.z));
    const float d3 = __fmaf_rn(lo4.w, lo4.w, __fmul_rn(la4.w, la4.w));
    lmin = fminf(lmin, fminf(fminf(d0, d1), fminf(d2, d3)));
  }

  // ---- T1 = 10th smallest of the 64 lane minima (lane-tagged u64 keys) ----
  float T1f;
  {
    unsigned long long kv =
        ((unsigned long long)__float_as_uint(lmin) << 32) | (unsigned)lane;
#pragma unroll
    for (int k = 0; k < NH_; ++k) {
      unsigned long long m = kv;
#pragma unroll
      for (int off = 32; off > 0; off >>= 1) {
        const unsigned long long o = __shfl_xor(m, off, 64);
        m = o < m ? o : m;
      }
      if (kv == m) kv = ~0ull;  // self-remove (unique by lane tag)
      if (k == NH_ - 1) T1f = __uint_as_float((unsigned)(m >> 32));
    }
    T1f = T1f * 1.000002f;  // margin: fma-vs-strict + sqrt-tie boundary
  }

  // ---- Pass B: collect candidate indices (d2 <= T1f), L3-resident re-read --
  for (int c = 0; c < NS_; c += 256) {
    const int s = c + lane * 4;
    const float4 lo4 = *(const float4*)(lon_row + s);
    const float4 la4 = *(const float4*)(lat_row + s);
    float dv[4];
    dv[0] = __fmaf_rn(lo4.x, lo4.x, __fmul_rn(la4.x, la4.x));
    dv[1] = __fmaf_rn(lo4.y, lo4.y, __fmul_rn(la4.y, la4.y));
    dv[2] = __fmaf_rn(lo4.z, lo4.z, __fmul_rn(la4.z, la4.z));
    dv[3] = __fmaf_rn(lo4.w, lo4.w, __fmul_rn(la4.w, la4.w));
    const float mn = fminf(fminf(dv[0], dv[1]), fminf(dv[2], dv[3]));
    if (mn <= T1f) {  // rare
#pragma unroll
      for (int j = 0; j < 4; ++j) {
        if (dv[j] <= T1f) {
          const int pos = atomicAdd(&cnt[wave], 1);
          if (pos < CAND_CAP) cand[wave][pos] = (unsigned)(s + j);
        }
      }
    }
  }
  __syncthreads();

  // ---- Final: exact strict-d top-10 over candidates (verified machinery) --
  const int ncand = min(cnt[wave], CAND_CAP);

  unsigned long long top[NH_];
#pragma unroll
  for (int i = 0; i < NH_; ++i) top[i] = ~0ull;

#pragma unroll
  for (int cc = 0; cc < CAND_CAP / 64; ++cc) {
    const int ci = lane + cc * 64;
    if (ci < ncand) {
      const unsigned s = cand[wave][ci];
      const float lo = lon_row[s];
      const float la = lat_row[s];
      // bit-exact numpy sequence: mul, mul, add, sqrt — all rn
      const float d = __fsqrt_rn(__fadd_rn(__fmul_rn(lo, lo),
                                           __fmul_rn(la, la)));
      unsigned long long p =
          ((unsigned long long)__float_as_uint(d) << 32) | s;
#pragma unroll
      for (int i = 0; i < NH_; ++i) {
        const bool lt = p < top[i];
        const unsigned long long mn2 = lt ? p : top[i];
        const unsigned long long mx2 = lt ? top[i] : p;
        top[i] = mn2;
        p = mx2;
      }
    }
  }

  unsigned long long resv = ~0ull;
  unsigned long long cur = top[0];
#pragma unroll
  for (int k = 0; k < NH_; ++k) {
    unsigned long long m = cur;
#pragma unroll
    for (int off = 32; off > 0; off >>= 1) {
      const unsigned long long o = __shfl_xor(m, off, 64);
      m = o < m ? o : m;
    }
    if (cur == m) {
#pragma unroll
      for (int i = 0; i < NH_ - 1; ++i) top[i] = top[i + 1];
      top[NH_ - 1] = ~0ull;
      cur = top[0];
    }
    if (lane == k) resv = m;
  }

  if (lane < NH_) {
    const unsigned s = (unsigned)(resv & 0xffffffffu);
    const float d = __uint_as_float((unsigned)(resv >> 32));
    out_d[t * NH_ + lane] = d;
    idx_out[t * NH_ + lane] = (int)s;
    out_lon[t * NH_ + lane] = lon_row[s];
    out_lat[t * NH_ + lane] = lat_row[s];
  }
}

// ---------------------------------------------------------------------------
// Kernel B: x_nearest gather. (VERIFIED PASSING — unchanged. Runs LAST.)
// ---------------------------------------------------------------------------
__global__ __launch_bounds__(256) void gather_kernel(
    const float* __restrict__ x, const int* __restrict__ idxbuf,
    float* __restrict__ out_xn)
{
  const int t = blockIdx.x;
  __shared__ int sidx[NH_];
  if (threadIdx.x < NH_) sidx[threadIdx.x] = idxbuf[t * NH_ + threadIdx.x];
  __syncthreads();
  for (int i = threadIdx.x; i < B_ * NH_ * (E_ / 4); i += 256) {  // 640 items
    const int e4 = i & 7;
    const int k = (i >> 3) % NH_;
    const int b = (i >> 3) / NH_;
    const int s = sidx[k];
    const float4 v = *(const float4*)(x + ((size_t)b * NS_ + s) * E_ + e4 * 4);
    *(float4*)(out_xn + (((size_t)b * NT_ + t) * NH_ + k) * E_ + e4 * 4) = v;
  }
}

// ---------------------------------------------------------------------------
// Kernel P: x (f32 [b][s][e]) -> XT2 (bf16, GEMM-chunked layout).
// (VERIFIED PASSING — unchanged.)
// ---------------------------------------------------------------------------
__global__ __launch_bounds__(256) void xprep_kernel(
    const float* __restrict__ x, unsigned short* __restrict__ XT2)
{
  __shared__ __align__(16) unsigned short T[32][136];
  const int b = blockIdx.y;
  const int s0 = blockIdx.x * 128;
  const int tid = threadIdx.x;
  const int eq = tid & 7, slq = tid >> 3;
#pragma unroll
  for (int r4 = 0; r4 < 4; ++r4) {
    const int sl = r4 * 32 + slq;
    const float4 v = *(const float4*)&x[((size_t)b * NS_ + s0 + sl) * E_ + eq * 4];
    T[eq * 4 + 0][sl] = f2bf(v.x);
    T[eq * 4 + 1][sl] = f2bf(v.y);
    T[eq * 4 + 2][sl] = f2bf(v.z);
    T[eq * 4 + 3][sl] = f2bf(v.w);
  }
  __syncthreads();
  const int r = tid & 31, cq = tid >> 5;
  const int be = b * 32 + r;
  const int sA = s0 + cq * 16;
  const int c = sA >> 6;
  const int kA = (sA >> 3) & 7;
  unsigned short* dst = XT2 + ((size_t)(c * 8 + kA) * 256 + be) * 8;
  *(ushort8_t*)dst = *(const ushort8_t*)&T[r][cq * 16];
  *(ushort8_t*)(dst + 2048) = *(const ushort8_t*)&T[r][cq * 16 + 8];
}

// ---------------------------------------------------------------------------
// Kernel C: x_inter via bf16 MFMA, double-buffered + shared B-fragments.
// (VERIFIED PASSING — unchanged.)
// ---------------------------------------------------------------------------
__global__ __launch_bounds__(512) void xinter_mfma(
    const unsigned short* __restrict__ XT2, const float* __restrict__ cs,
    const float* __restrict__ ct, float* __restrict__ out_xi)
{
#pragma clang fp contract(off)
  __shared__ __align__(16) unsigned short Xl[2][8][256][8];  // 64 KB
  __shared__ __align__(16) unsigned short Rl[2][8][16][8];   // 4 KB
  __shared__ float RsumP[16][32];
  __shared__ float RsumInv[32];

  const int tid = threadIdx.x;
  const int w = tid >> 6, l = tid & 63;
  const int mg = w >> 1, ng = w & 1;
  const int lcol = l & 15, lkg = l >> 4;
  const int t0 = blockIdx.x * 32;

  const int gt = tid & 31;
  const int gq = tid >> 5;
  const int gng = gt >> 4, glc = gt & 15;
  const int gk = gq >> 1;
  const int gsl = (gq & 1) * 4;
  const float2 ctg = ((const float2*)ct)[t0 + gt];
  const float t2g = ctg.x * ctg.x + ctg.y * ctg.y;   // strict rn
  float rpart = 0.f;

  const int t = t0 + ng * 16 + lcol;

  f32x4 acc[4];
#pragma unroll
  for (int m = 0; m < 4; ++m)
#pragma unroll
    for (int j = 0; j < 4; ++j) acc[m][j] = 0.f;

#define STAGE_CHUNK(buf, ch)                                                 \
  {                                                                          \
    const unsigned short* gsrc =                                             \
        XT2 + ((size_t)(ch) * 8 + w) * 2048 + (size_t)l * 8;                 \
    _Pragma("unroll")                                                        \
    for (int bg = 0; bg < 4; ++bg) {                                         \
      __builtin_amdgcn_global_load_lds(                                      \
          (const __attribute__((address_space(1))) void*)(gsrc + bg * 512),  \
          (__attribute__((address_space(3))) void*)&Xl[buf][w][bg * 64][0],  \
          16, 0, 0);                                                         \
    }                                                                        \
  }

  STAGE_CHUNK(0, 0);
  asm volatile("s_waitcnt vmcnt(0)" ::: "memory");
  __builtin_amdgcn_s_barrier();

  int cur = 0;
  for (int c = 0; c < NCH_; ++c) {
    if (c + 1 < NCH_) STAGE_CHUNK(cur ^ 1, c + 1);

    {
      const int sb = c * 64 + gq * 4;
      const float4 cA = *(const float4*)&cs[2 * sb];
      const float4 cB = *(const float4*)&cs[2 * sb + 4];
      const float sxv[4] = {cA.x, cA.z, cB.x, cB.z};
      const float syv[4] = {cA.y, cA.w, cB.y, cB.w};
      ushort4_t ro;
#pragma unroll
      for (int j = 0; j < 4; ++j) {
        const float sx = sxv[j], sy = syv[j];
        const float s2 = sx * sx + sy * sy;        // strict rn
        const float p0 = ctg.x * sx;               // strict rn product, k=0
        const float dot = fmaf(ctg.y, sy, p0);     // explicit fma, k=1
        const float ts = t2g + s2;                 // strict rn
        float d2 = ts - 2.0f * dot;                // 2*dot exact; strict sub
        d2 = fmaxf(d2, 1e-12f);
        const float r = __builtin_amdgcn_rsqf(d2);
        const unsigned short ub = f2bf(r);
        ro[j] = ub;
        rpart += bf2f(ub);
      }
      *(ushort4_t*)&Rl[gng][gk][glc][gsl] = ro;
    }
    asm volatile("s_waitcnt lgkmcnt(0)" ::: "memory");
    __builtin_amdgcn_s_barrier();

#pragma unroll
    for (int half = 0; half < 2; ++half) {
      const bf16x8 Bf = *(const bf16x8*)&Rl[ng][half * 4 + lkg][lcol][0];
#pragma unroll
      for (int m = 0; m < 4; ++m) {
        const bf16x8 a =
            *(const bf16x8*)&Xl[cur][half * 4 + lkg][(mg * 4 + m) * 16 + lcol][0];
        acc[m] = __builtin_amdgcn_mfma_f32_16x16x32_bf16(a, Bf, acc[m], 0, 0, 0);
      }
    }

    asm volatile("s_waitcnt vmcnt(0)" ::: "memory");
    __builtin_amdgcn_s_barrier();
    cur ^= 1;
  }
#undef STAGE_CHUNK

  RsumP[gq][gt] = rpart;
  asm volatile("s_waitcnt lgkmcnt(0)" ::: "memory");
  __builtin_amdgcn_s_barrier();
  if (tid < 32) {
    float ssum = 0.f;
#pragma unroll
    for (int q = 0; q < 16; ++q) ssum += RsumP[q][tid];
    RsumInv[tid] = 1.0f / ssum;
  }
  asm volatile("s_waitcnt lgkmcnt(0)" ::: "memory");
  __builtin_amdgcn_s_barrier();
  const float ri = RsumInv[ng * 16 + lcol];

#pragma unroll
  for (int m = 0; m < 4; ++m) {
    const int be0 = (mg * 4 + m) * 16 + lkg * 4;
    const int b = be0 >> 5, e = be0 & 31;
    float4 o;
    o.x = acc[m][0] * ri;
    o.y = acc[m][1] * ri;
    o.z = acc[m][2] * ri;
    o.w = acc[m][3] * ri;
    *(float4*)&out_xi[((size_t)b * NT_ + t) * E_ + e] = o;
  }
}

// ---------------------------------------------------------------------------
extern "C" void kernel_launch(void* const* d_in, const int* in_sizes, int n_in,
                              void* d_out, int out_size, void* d_ws,
                              size_t ws_size, hipStream_t stream)
{
  const float* x       = (const float*)d_in[0];
  const float* rel_lon = (const float*)d_in[1];
  const float* rel_lat = (const float*)d_in[2];
  const float* cs      = (const float*)d_in[3];
  const float* ct      = (const float*)d_in[4];

  float* out = (float*)d_out;
  float* out_xn  = out;                                // (8,8192,10,32)
  float* out_xi  = out + (size_t)B_ * NT_ * NH_ * E_;  // (8,8192,32)
  float* out_d   = out_xi + (size_t)B_ * NT_ * E_;     // (8192,10)
  float* out_lon = out_d + (size_t)NT_ * NH_;
  float* out_lat = out_lon + (size_t)NT_ * NH_;

  int* idxbuf = (int*)d_ws;                       // 328 KB
  unsigned short* XT2 = (unsigned short*)out_xn;  // 4 MB scratch in out_xn;
                                                  // gather_kernel rewrites it.

  topk_kernel<<<NT_ / 4, 256, 0, stream>>>(rel_lon, rel_lat, out_d, out_lon,
                                           out_lat, idxbuf);
  xprep_kernel<<<dim3(NS_ / 128, B_), 256, 0, stream>>>(x, XT2);
  xinter_mfma<<<NT_ / 32, 512, 0, stream>>>(XT2, cs, ct, out_xi);
  gather_kernel<<<NT_, 256, 0, stream>>>(x, idxbuf, out_xn);
}

// Round 10
// 293.125 us; speedup vs baseline: 1.2402x; 1.2402x over previous
//
#include <hip/hip_runtime.h>
#include <hip/hip_bf16.h>
#include <stdint.h>

#define B_   8
#define NS_  8192
#define E_   32
#define NT_  8192
#define NH_  10
#define NCH_ 128   // NS_/64 K-chunks
#define CAND_CAP 512

typedef __bf16 bf16x8 __attribute__((ext_vector_type(8)));
typedef float  f32x4  __attribute__((ext_vector_type(4)));
typedef unsigned short ushort8_t __attribute__((ext_vector_type(8)));
typedef unsigned short ushort4_t __attribute__((ext_vector_type(4)));

static __device__ inline unsigned short f2bf(float f) {
  __hip_bfloat16 h = __float2bfloat16(f);
  return *reinterpret_cast<unsigned short*>(&h);
}
static __device__ inline float bf2f(unsigned short u) {
  __hip_bfloat16 h;
  *reinterpret_cast<unsigned short*>(&h) = u;
  return __bfloat162float(h);
}

// 10th-smallest of the 64 per-lane values (lane-tagged u64 keys; exact).
static __device__ inline float tenth_smallest(float v, int lane) {
  unsigned long long kv =
      ((unsigned long long)__float_as_uint(v) << 32) | (unsigned)lane;
  float out = 0.f;
#pragma unroll
  for (int k = 0; k < NH_; ++k) {
    unsigned long long m = kv;
#pragma unroll
    for (int off = 32; off > 0; off >>= 1) {
      const unsigned long long o = __shfl_xor(m, off, 64);
      m = o < m ? o : m;
    }
    if (kv == m) kv = ~0ull;  // self-remove (unique by lane tag)
    if (k == NH_ - 1) out = __uint_as_float((unsigned)(m >> 32));
  }
  return out;
}

// ---------------------------------------------------------------------------
// Kernel A: per-target-row top-10 smallest d = sqrt(lon^2+lat^2).
// v10: SINGLE-pass lazy-threshold filter (round 9's two-pass re-read 536MB
// from HBM — L3 can't hold it; this streams once).
//  Group 0 (2048 elems): d2=fma form, per-lane min only. T = 10th-smallest
//    of lane minima * 1.000002 (proven bound+margin, round 9). Re-scan
//    group 0 immediately (L1/L2-hot) to collect its candidates.
//  Groups 1-3: collect while streaming with current T; tighten T after g1.
//    Superset property: true top-10 elems have d2 <= T_final <= any earlier T.
//  Final: exact strict-rn d, (d_bits<<32)|s key, cascade + wave merge over
//    <=512 candidates — bit-identical to numpy incl. tie-breaking.
// ---------------------------------------------------------------------------
__global__ __launch_bounds__(256) void topk_kernel(
    const float* __restrict__ rel_lon, const float* __restrict__ rel_lat,
    float* __restrict__ out_d, float* __restrict__ out_lon,
    float* __restrict__ out_lat, int* __restrict__ idx_out)
{
  __shared__ int cnt[4];
  __shared__ unsigned int cand[4][CAND_CAP];

  const int wave = threadIdx.x >> 6;
  const int lane = threadIdx.x & 63;
  const int t = blockIdx.x * 4 + wave;
  const float* lon_row = rel_lon + (size_t)t * NS_;
  const float* lat_row = rel_lat + (size_t)t * NS_;

  if (lane == 0) cnt[wave] = 0;

  float lmin = __uint_as_float(0x7f800000u);  // +inf
  float T = 0.f;

#define D2_PACKET(c)                                                       \
  const int s = (c) * 256 + lane * 4;                                      \
  const float4 lo4 = *(const float4*)(lon_row + s);                        \
  const float4 la4 = *(const float4*)(lat_row + s);                        \
  float dv[4];                                                             \
  dv[0] = __fmaf_rn(lo4.x, lo4.x, __fmul_rn(la4.x, la4.x));                \
  dv[1] = __fmaf_rn(lo4.y, lo4.y, __fmul_rn(la4.y, la4.y));                \
  dv[2] = __fmaf_rn(lo4.z, lo4.z, __fmul_rn(la4.z, la4.z));                \
  dv[3] = __fmaf_rn(lo4.w, lo4.w, __fmul_rn(la4.w, la4.w));                \
  const float mn = fminf(fminf(dv[0], dv[1]), fminf(dv[2], dv[3]));

#define COLLECT()                                                          \
  if (mn <= T) {                                                           \
    _Pragma("unroll")                                                      \
    for (int j = 0; j < 4; ++j) {                                          \
      if (dv[j] <= T) {                                                    \
        const int pos = atomicAdd(&cnt[wave], 1);                          \
        if (pos < CAND_CAP) cand[wave][pos] = (unsigned)(s + j);           \
      }                                                                    \
    }                                                                      \
  }

  // ---- group 0: min only ----
  for (int c = 0; c < 8; ++c) {
    D2_PACKET(c)
    lmin = fminf(lmin, mn);
  }
  T = tenth_smallest(lmin, lane) * 1.000002f;
  // ---- re-scan group 0 while L1/L2-hot ----
  for (int c = 0; c < 8; ++c) {
    D2_PACKET(c)
    COLLECT()
  }
  // ---- group 1: stream + collect ----
  for (int c = 8; c < 16; ++c) {
    D2_PACKET(c)
    lmin = fminf(lmin, mn);
    COLLECT()
  }
  T = fminf(T, tenth_smallest(lmin, lane) * 1.000002f);
  // ---- groups 2-3 ----
  for (int c = 16; c < 32; ++c) {
    D2_PACKET(c)
    COLLECT()
  }
#undef D2_PACKET
#undef COLLECT

  __syncthreads();

  // ---- Final: exact strict-d top-10 over candidates (verified machinery) --
  const int ncand = min(cnt[wave], CAND_CAP);

  unsigned long long top[NH_];
#pragma unroll
  for (int i = 0; i < NH_; ++i) top[i] = ~0ull;

#pragma unroll
  for (int cc = 0; cc < CAND_CAP / 64; ++cc) {
    const int ci = lane + cc * 64;
    if (ci < ncand) {
      const unsigned s = cand[wave][ci];
      const float lo = lon_row[s];
      const float la = lat_row[s];
      // bit-exact numpy sequence: mul, mul, add, sqrt — all rn
      const float d = __fsqrt_rn(__fadd_rn(__fmul_rn(lo, lo),
                                           __fmul_rn(la, la)));
      unsigned long long p =
          ((unsigned long long)__float_as_uint(d) << 32) | s;
#pragma unroll
      for (int i = 0; i < NH_; ++i) {
        const bool lt = p < top[i];
        const unsigned long long mn2 = lt ? p : top[i];
        const unsigned long long mx2 = lt ? top[i] : p;
        top[i] = mn2;
        p = mx2;
      }
    }
  }

  unsigned long long resv = ~0ull;
  unsigned long long cur = top[0];
#pragma unroll
  for (int k = 0; k < NH_; ++k) {
    unsigned long long m = cur;
#pragma unroll
    for (int off = 32; off > 0; off >>= 1) {
      const unsigned long long o = __shfl_xor(m, off, 64);
      m = o < m ? o : m;
    }
    if (cur == m) {
#pragma unroll
      for (int i = 0; i < NH_ - 1; ++i) top[i] = top[i + 1];
      top[NH_ - 1] = ~0ull;
      cur = top[0];
    }
    if (lane == k) resv = m;
  }

  if (lane < NH_) {
    const unsigned s = (unsigned)(resv & 0xffffffffu);
    const float d = __uint_as_float((unsigned)(resv >> 32));
    out_d[t * NH_ + lane] = d;
    idx_out[t * NH_ + lane] = (int)s;
    out_lon[t * NH_ + lane] = lon_row[s];
    out_lat[t * NH_ + lane] = lat_row[s];
  }
}

// ---------------------------------------------------------------------------
// Kernel B: x_nearest gather. (VERIFIED PASSING — unchanged. Runs LAST.)
// ---------------------------------------------------------------------------
__global__ __launch_bounds__(256) void gather_kernel(
    const float* __restrict__ x, const int* __restrict__ idxbuf,
    float* __restrict__ out_xn)
{
  const int t = blockIdx.x;
  __shared__ int sidx[NH_];
  if (threadIdx.x < NH_) sidx[threadIdx.x] = idxbuf[t * NH_ + threadIdx.x];
  __syncthreads();
  for (int i = threadIdx.x; i < B_ * NH_ * (E_ / 4); i += 256) {  // 640 items
    const int e4 = i & 7;
    const int k = (i >> 3) % NH_;
    const int b = (i >> 3) / NH_;
    const int s = sidx[k];
    const float4 v = *(const float4*)(x + ((size_t)b * NS_ + s) * E_ + e4 * 4);
    *(float4*)(out_xn + (((size_t)b * NT_ + t) * NH_ + k) * E_ + e4 * 4) = v;
  }
}

// ---------------------------------------------------------------------------
// Kernel P: x (f32 [b][s][e]) -> XT2 (bf16, GEMM-chunked layout).
// (VERIFIED PASSING — unchanged.)
// ---------------------------------------------------------------------------
__global__ __launch_bounds__(256) void xprep_kernel(
    const float* __restrict__ x, unsigned short* __restrict__ XT2)
{
  __shared__ __align__(16) unsigned short T[32][136];
  const int b = blockIdx.y;
  const int s0 = blockIdx.x * 128;
  const int tid = threadIdx.x;
  const int eq = tid & 7, slq = tid >> 3;
#pragma unroll
  for (int r4 = 0; r4 < 4; ++r4) {
    const int sl = r4 * 32 + slq;
    const float4 v = *(const float4*)&x[((size_t)b * NS_ + s0 + sl) * E_ + eq * 4];
    T[eq * 4 + 0][sl] = f2bf(v.x);
    T[eq * 4 + 1][sl] = f2bf(v.y);
    T[eq * 4 + 2][sl] = f2bf(v.z);
    T[eq * 4 + 3][sl] = f2bf(v.w);
  }
  __syncthreads();
  const int r = tid & 31, cq = tid >> 5;
  const int be = b * 32 + r;
  const int sA = s0 + cq * 16;
  const int c = sA >> 6;
  const int kA = (sA >> 3) & 7;
  unsigned short* dst = XT2 + ((size_t)(c * 8 + kA) * 256 + be) * 8;
  *(ushort8_t*)dst = *(const ushort8_t*)&T[r][cq * 16];
  *(ushort8_t*)(dst + 2048) = *(const ushort8_t*)&T[r][cq * 16 + 8];
}

// ---------------------------------------------------------------------------
// Kernel C: x_inter via bf16 MFMA, double-buffered + shared B-fragments.
// (VERIFIED PASSING — unchanged.)
// ---------------------------------------------------------------------------
__global__ __launch_bounds__(512) void xinter_mfma(
    const unsigned short* __restrict__ XT2, const float* __restrict__ cs,
    const float* __restrict__ ct, float* __restrict__ out_xi)
{
#pragma clang fp contract(off)
  __shared__ __align__(16) unsigned short Xl[2][8][256][8];  // 64 KB
  __shared__ __align__(16) unsigned short Rl[2][8][16][8];   // 4 KB
  __shared__ float RsumP[16][32];
  __shared__ float RsumInv[32];

  const int tid = threadIdx.x;
  const int w = tid >> 6, l = tid & 63;
  const int mg = w >> 1, ng = w & 1;
  const int lcol = l & 15, lkg = l >> 4;
  const int t0 = blockIdx.x * 32;

  const int gt = tid & 31;
  const int gq = tid >> 5;
  const int gng = gt >> 4, glc = gt & 15;
  const int gk = gq >> 1;
  const int gsl = (gq & 1) * 4;
  const float2 ctg = ((const float2*)ct)[t0 + gt];
  const float t2g = ctg.x * ctg.x + ctg.y * ctg.y;   // strict rn
  float rpart = 0.f;

  const int t = t0 + ng * 16 + lcol;

  f32x4 acc[4];
#pragma unroll
  for (int m = 0; m < 4; ++m)
#pragma unroll
    for (int j = 0; j < 4; ++j) acc[m][j] = 0.f;

#define STAGE_CHUNK(buf, ch)                                                 \
  {                                                                          \
    const unsigned short* gsrc =                                             \
        XT2 + ((size_t)(ch) * 8 + w) * 2048 + (size_t)l * 8;                 \
    _Pragma("unroll")                                                        \
    for (int bg = 0; bg < 4; ++bg) {                                         \
      __builtin_amdgcn_global_load_lds(                                      \
          (const __attribute__((address_space(1))) void*)(gsrc + bg * 512),  \
          (__attribute__((address_space(3))) void*)&Xl[buf][w][bg * 64][0],  \
          16, 0, 0);                                                         \
    }                                                                        \
  }

  STAGE_CHUNK(0, 0);
  asm volatile("s_waitcnt vmcnt(0)" ::: "memory");
  __builtin_amdgcn_s_barrier();

  int cur = 0;
  for (int c = 0; c < NCH_; ++c) {
    if (c + 1 < NCH_) STAGE_CHUNK(cur ^ 1, c + 1);

    {
      const int sb = c * 64 + gq * 4;
      const float4 cA = *(const float4*)&cs[2 * sb];
      const float4 cB = *(const float4*)&cs[2 * sb + 4];
      const float sxv[4] = {cA.x, cA.z, cB.x, cB.z};
      const float syv[4] = {cA.y, cA.w, cB.y, cB.w};
      ushort4_t ro;
#pragma unroll
      for (int j = 0; j < 4; ++j) {
        const float sx = sxv[j], sy = syv[j];
        const float s2 = sx * sx + sy * sy;        // strict rn
        const float p0 = ctg.x * sx;               // strict rn product, k=0
        const float dot = fmaf(ctg.y, sy, p0);     // explicit fma, k=1
        const float ts = t2g + s2;                 // strict rn
        float d2 = ts - 2.0f * dot;                // 2*dot exact; strict sub
        d2 = fmaxf(d2, 1e-12f);
        const float r = __builtin_amdgcn_rsqf(d2);
        const unsigned short ub = f2bf(r);
        ro[j] = ub;
        rpart += bf2f(ub);
      }
      *(ushort4_t*)&Rl[gng][gk][glc][gsl] = ro;
    }
    asm volatile("s_waitcnt lgkmcnt(0)" ::: "memory");
    __builtin_amdgcn_s_barrier();

#pragma unroll
    for (int half = 0; half < 2; ++half) {
      const bf16x8 Bf = *(const bf16x8*)&Rl[ng][half * 4 + lkg][lcol][0];
#pragma unroll
      for (int m = 0; m < 4; ++m) {
        const bf16x8 a =
            *(const bf16x8*)&Xl[cur][half * 4 + lkg][(mg * 4 + m) * 16 + lcol][0];
        acc[m] = __builtin_amdgcn_mfma_f32_16x16x32_bf16(a, Bf, acc[m], 0, 0, 0);
      }
    }

    asm volatile("s_waitcnt vmcnt(0)" ::: "memory");
    __builtin_amdgcn_s_barrier();
    cur ^= 1;
  }
#undef STAGE_CHUNK

  RsumP[gq][gt] = rpart;
  asm volatile("s_waitcnt lgkmcnt(0)" ::: "memory");
  __builtin_amdgcn_s_barrier();
  if (tid < 32) {
    float ssum = 0.f;
#pragma unroll
    for (int q = 0; q < 16; ++q) ssum += RsumP[q][tid];
    RsumInv[tid] = 1.0f / ssum;
  }
  asm volatile("s_waitcnt lgkmcnt(0)" ::: "memory");
  __builtin_amdgcn_s_barrier();
  const float ri = RsumInv[ng * 16 + lcol];

#pragma unroll
  for (int m = 0; m < 4; ++m) {
    const int be0 = (mg * 4 + m) * 16 + lkg * 4;
    const int b = be0 >> 5, e = be0 & 31;
    float4 o;
    o.x = acc[m][0] * ri;
    o.y = acc[m][1] * ri;
    o.z = acc[m][2] * ri;
    o.w = acc[m][3] * ri;
    *(float4*)&out_xi[((size_t)b * NT_ + t) * E_ + e] = o;
  }
}

// ---------------------------------------------------------------------------
extern "C" void kernel_launch(void* const* d_in, const int* in_sizes, int n_in,
                              void* d_out, int out_size, void* d_ws,
                              size_t ws_size, hipStream_t stream)
{
  const float* x       = (const float*)d_in[0];
  const float* rel_lon = (const float*)d_in[1];
  const float* rel_lat = (const float*)d_in[2];
  const float* cs      = (const float*)d_in[3];
  const float* ct      = (const float*)d_in[4];

  float* out = (float*)d_out;
  float* out_xn  = out;                                // (8,8192,10,32)
  float* out_xi  = out + (size_t)B_ * NT_ * NH_ * E_;  // (8,8192,32)
  float* out_d   = out_xi + (size_t)B_ * NT_ * E_;     // (8192,10)
  float* out_lon = out_d + (size_t)NT_ * NH_;
  float* out_lat = out_lon + (size_t)NT_ * NH_;

  int* idxbuf = (int*)d_ws;                       // 328 KB
  unsigned short* XT2 = (unsigned short*)out_xn;  // 4 MB scratch in out_xn;
                                                  // gather_kernel rewrites it.

  topk_kernel<<<NT_ / 4, 256, 0, stream>>>(rel_lon, rel_lat, out_d, out_lon,
                                           out_lat, idxbuf);
  xprep_kernel<<<dim3(NS_ / 128, B_), 256, 0, stream>>>(x, XT2);
  xinter_mfma<<<NT_ / 32, 512, 0, stream>>>(XT2, cs, ct, out_xi);
  gather_kernel<<<NT_, 256, 0, stream>>>(x, idxbuf, out_xn);
}